// Round 6
// baseline (680.729 us; speedup 1.0000x reference)
//
#include <hip/hip_runtime.h>

// Quantizer via bf16x3-split MFMA GEMM + exact-fp32 recheck of near-ties.
//   x: [16,64,32,32] fp32, embed: [64,8192] fp32
//   out[row][c] = embedT[argmax_j (f_row.e_j - ||e_j||^2/2)][c]
//
// R6: R5 structure (no LDS / no barriers in hot loop; codes stream from
// global into MFMA A-operands; pixels resident as B-operands) with:
//  - pixel fragments PINNED in VGPRs via asm volatile "+v" (R5's compiler
//    sank the loop-invariant loads into the loop -> VGPR_Count 44, latency-bound)
//  - 7-op quad epilogue (b2 = second-best quad-max; within-quad resolved
//    exactly in reduce_rows with 4 fp32 dots)
//  - margin 2e-3 (>=4x realized bf16x3 error) + coalesced recheck over embed

typedef __attribute__((ext_vector_type(8))) __bf16 bf16x8;
typedef __attribute__((ext_vector_type(4))) float f32x4;
typedef unsigned int u32;
typedef unsigned long long u64;

union frag_cast { f32x4 f; bf16x8 b; };
__device__ __forceinline__ bf16x8 as_bf16x8(f32x4 v) { frag_cast u; u.f = v; return u.b; }

#define N_ROWS  16384
#define E_DIM   64
#define N_EMBED 8192
#define NCHUNK  8
#define COLS_PER_BLOCK (N_EMBED / NCHUNK)   // 1024
#define N_ST (COLS_PER_BLOCK / 64)          // 16
#define ROWS_PER_BLOCK 128                  // 4 waves x 32 pixels
#define N_ROWBLK (N_ROWS / ROWS_PER_BLOCK)  // 128
#define MARGIN_THR 2e-3f

// ---- workspace byte offsets (~9.7 MB total)
#define WS_AH   0u              // pixel hi  [16384][64] bf16
#define WS_AL   (2u << 20)      // pixel lo
#define WS_BH   (4u << 20)      // code  hi  [8192][64] bf16 (128 B/code)
#define WS_BL   (5u << 20)      // code  lo
#define WS_ET   (6u << 20)      // embedT fp32 [8192][64]
#define WS_BIAS (8u << 20)      // -||e_j||^2/2
#define WS_PB1  (WS_BIAS + (64u << 10))
#define WS_PI1  (WS_PB1 + (512u << 10))
#define WS_PB2  (WS_PI1 + (512u << 10))
#define WS_FIDX (WS_PB2 + (512u << 10))
#define WS_FLAG (WS_FIDX + (64u << 10))
#define WS_CNT  (WS_FLAG + (64u << 10))

__device__ __forceinline__ u32 f32_key(float s) {
    u32 u = __float_as_uint(s);
    return (u & 0x80000000u) ? ~u : (u | 0x80000000u);
}

// ---- K1: prep. Blocks 0..255: split x -> A_hi/A_lo [row][64] bf16.
//          Blocks 256..383: transpose embed tile -> embedT fp32, B_hi/B_lo, bias.
__global__ __launch_bounds__(256) void prep(
        const float* __restrict__ x, const float* __restrict__ embed, char* ws) {
    __shared__ float tile[64][65];
    __bf16* Ah = (__bf16*)(ws + WS_AH);
    __bf16* Al = (__bf16*)(ws + WS_AL);
    __bf16* Bh = (__bf16*)(ws + WS_BH);
    __bf16* Bl = (__bf16*)(ws + WS_BL);
    float*  eT = (float*)(ws + WS_ET);
    float*  bias = (float*)(ws + WS_BIAS);
    const int t = threadIdx.x;
    const int blk = blockIdx.x;

    if (blk < 256) {
        const int b = blk >> 4, p0 = (blk & 15) * 64;
        {
            const int c = t >> 2, seg = (t & 3) * 16;
            const float* src = x + b * 65536 + c * 1024 + p0 + seg;
#pragma unroll
            for (int i = 0; i < 16; ++i) tile[c][seg + i] = src[i];
        }
        __syncthreads();
        const int p = t >> 2, cq = (t & 3) * 16;
        const long row = b * 1024 + p0 + p;
        bf16x8 vh0, vh1, vl0, vl1;
#pragma unroll
        for (int i = 0; i < 16; ++i) {
            float f = tile[cq + i][p];
            __bf16 h = (__bf16)f;
            __bf16 l = (__bf16)(f - (float)h);
            if (i < 8) { vh0[i] = h; vl0[i] = l; }
            else       { vh1[i - 8] = h; vl1[i - 8] = l; }
        }
        *(bf16x8*)(Ah + row * 64 + cq) = vh0;
        *(bf16x8*)(Ah + row * 64 + cq + 8) = vh1;
        *(bf16x8*)(Al + row * 64 + cq) = vl0;
        *(bf16x8*)(Al + row * 64 + cq + 8) = vl1;
    } else {
        if (blk == 256 && t == 0) *(int*)(ws + WS_CNT) = 0;
        const int jbase = (blk - 256) * 64;
        {
            const int c = t >> 2, seg = (t & 3) * 16;
            const float* src = embed + c * N_EMBED + jbase + seg;
#pragma unroll
            for (int i = 0; i < 16; ++i) tile[c][seg + i] = src[i];
        }
        __syncthreads();
        if (t < 64) {
            float s = 0.f;
#pragma unroll
            for (int c = 0; c < 64; ++c) { float v = tile[c][t]; s = fmaf(v, v, s); }
            bias[jbase + t] = -0.5f * s;
        }
        const int jl = t >> 2, cq = (t & 3) * 16;
        const long row = jbase + jl;
        bf16x8 vh0, vh1, vl0, vl1;
#pragma unroll
        for (int i = 0; i < 16; ++i) {
            float f = tile[cq + i][jl];
            eT[row * 64 + cq + i] = f;
            __bf16 h = (__bf16)f;
            __bf16 l = (__bf16)(f - (float)h);
            if (i < 8) { vh0[i] = h; vl0[i] = l; }
            else       { vh1[i - 8] = h; vl1[i - 8] = l; }
        }
        *(bf16x8*)(Bh + row * 64 + cq) = vh0;
        *(bf16x8*)(Bh + row * 64 + cq + 8) = vh1;
        *(bf16x8*)(Bl + row * 64 + cq) = vl0;
        *(bf16x8*)(Bl + row * 64 + cq + 8) = vl1;
    }
}

// ---- K2: MFMA GEMM + running (quad-max top-2) argmax. 1024 blocks, 4/CU.
__global__ __launch_bounds__(256, 4) void qdist(const char* __restrict__ ws_c, char* ws) {
    const __bf16* Ah = (const __bf16*)(ws_c + WS_AH);
    const __bf16* Al = (const __bf16*)(ws_c + WS_AL);
    const char* ChB = ws_c + WS_BH;    // code hi, 128 B per code
    const char* ClB = ws_c + WS_BL;
    const float* biasg = (const float*)(ws_c + WS_BIAS);
    float* pb1 = (float*)(ws + WS_PB1);
    int*   pi1 = (int*)(ws + WS_PI1);
    float* pb2 = (float*)(ws + WS_PB2);

    const int t = threadIdx.x;
    const int wv = t >> 6, lane = t & 63, ln = lane & 15, q = lane >> 4;
    const int rb = blockIdx.x >> 3, chunk = blockIdx.x & 7;
    const int row0 = rb * ROWS_PER_BLOCK;
    const int col0 = chunk * COLS_PER_BLOCK;

    // resident pixel fragments (B-operand): 2 pixel-tiles x 2 K-halves x {hi,lo}
    f32x4 pfh[2][2], pfl[2][2];
#pragma unroll
    for (int nt = 0; nt < 2; ++nt) {
        long row = row0 + wv * 32 + nt * 16 + ln;
        long base = row * 64 + q * 8;
        pfh[nt][0] = *(const f32x4*)(Ah + base);
        pfh[nt][1] = *(const f32x4*)(Ah + base + 32);
        pfl[nt][0] = *(const f32x4*)(Al + base);
        pfl[nt][1] = *(const f32x4*)(Al + base + 32);
    }
    // pin: volatile asm barrier — scheduler cannot sink/remat these loads into
    // the loop (R5: it did exactly that, VGPR_Count 44, latency-bound, 136 us)
    asm volatile("" : "+v"(pfh[0][0]), "+v"(pfh[0][1]), "+v"(pfh[1][0]), "+v"(pfh[1][1]),
                      "+v"(pfl[0][0]), "+v"(pfl[0][1]), "+v"(pfl[1][0]), "+v"(pfl[1][1]));

    float b1[2] = {-3.4e38f, -3.4e38f};
    float b2[2] = {-3.4e38f, -3.4e38f};
    int   iq[2] = {0, 0};

    const int laneoff = ln * 128 + q * 16;   // byte offset within a 16-code tile

#pragma unroll 2
    for (int st = 0; st < N_ST; ++st) {
#pragma unroll
        for (int ct = 0; ct < 4; ++ct) {
            const int cbase = col0 + st * 64 + ct * 16;   // first code of tile
            const char* ch = ChB + ((size_t)cbase << 7);
            const char* cl = ClB + ((size_t)cbase << 7);
            // code fragments (A-operand): coalesced 1KB wave loads
            bf16x8 ah0 = *(const bf16x8*)(ch + laneoff);
            bf16x8 ah1 = *(const bf16x8*)(ch + laneoff + 64);
            bf16x8 al0 = *(const bf16x8*)(cl + laneoff);
            bf16x8 al1 = *(const bf16x8*)(cl + laneoff + 64);
            f32x4 bv = *(const f32x4*)(biasg + cbase + q * 4);  // bias for 4 codes
            const int jq = cbase + q * 4;
#pragma unroll
            for (int nt = 0; nt < 2; ++nt) {
                f32x4 acc = __builtin_amdgcn_mfma_f32_16x16x32_bf16(al0, as_bf16x8(pfh[nt][0]), bv, 0, 0, 0);
                acc = __builtin_amdgcn_mfma_f32_16x16x32_bf16(al1, as_bf16x8(pfh[nt][1]), acc, 0, 0, 0);
                acc = __builtin_amdgcn_mfma_f32_16x16x32_bf16(ah0, as_bf16x8(pfl[nt][0]), acc, 0, 0, 0);
                acc = __builtin_amdgcn_mfma_f32_16x16x32_bf16(ah1, as_bf16x8(pfl[nt][1]), acc, 0, 0, 0);
                acc = __builtin_amdgcn_mfma_f32_16x16x32_bf16(ah0, as_bf16x8(pfh[nt][0]), acc, 0, 0, 0);
                acc = __builtin_amdgcn_mfma_f32_16x16x32_bf16(ah1, as_bf16x8(pfh[nt][1]), acc, 0, 0, 0);
                // quad max (4 codes of one pixel): 7 VALU total
                float mx = fmaxf(fmaxf(acc[0], acc[1]), fmaxf(acc[2], acc[3]));
                b2[nt] = fmaxf(b2[nt], fminf(b1[nt], mx));   // 2nd-best quad-max
                bool gt = mx > b1[nt];
                b1[nt] = fmaxf(b1[nt], mx);
                iq[nt] = gt ? jq : iq[nt];
            }
        }
    }

    // merge across the 4 quads (same pixel lives in lanes ln, ln+16, ln+32, ln+48)
#pragma unroll
    for (int m = 16; m < 64; m <<= 1) {
#pragma unroll
        for (int nt = 0; nt < 2; ++nt) {
            float o1 = __shfl_xor(b1[nt], m);
            int   oi = __shfl_xor(iq[nt], m);
            float o2 = __shfl_xor(b2[nt], m);
            b2[nt] = fmaxf(fmaxf(fminf(b1[nt], o1), o2), b2[nt]);
            bool take = (o1 > b1[nt]) || (o1 == b1[nt] && oi < iq[nt]);
            if (take) { b1[nt] = o1; iq[nt] = oi; }
        }
    }
    if (q == 0) {
#pragma unroll
        for (int nt = 0; nt < 2; ++nt) {
            int pixel = row0 + wv * 32 + nt * 16 + ln;
            int o = chunk * N_ROWS + pixel;
            pb1[o] = b1[nt];
            pi1[o] = iq[nt];
            pb2[o] = b2[nt];
        }
    }
}

// ---- K3: merge chunks per row; exact fp32 pick within winning quad;
//          flag near-ties (quad-max margin) for full exact recheck.
__global__ __launch_bounds__(256) void reduce_rows(const float* __restrict__ x, char* ws) {
    const float* pb1 = (const float*)(ws + WS_PB1);
    const int*   pi1 = (const int*)(ws + WS_PI1);
    const float* pb2 = (const float*)(ws + WS_PB2);
    const float* eT = (const float*)(ws + WS_ET);
    const float* bias = (const float*)(ws + WS_BIAS);
    int* fidx = (int*)(ws + WS_FIDX);
    int* flags = (int*)(ws + WS_FLAG);
    int* cnt = (int*)(ws + WS_CNT);
    const int row = blockIdx.x * 256 + threadIdx.x;

    float b1 = pb1[row]; int iq = pi1[row]; float b2 = pb2[row];
#pragma unroll
    for (int ch = 1; ch < NCHUNK; ++ch) {
        float o1 = pb1[ch * N_ROWS + row];
        int   oi = pi1[ch * N_ROWS + row];
        float o2 = pb2[ch * N_ROWS + row];
        b2 = fmaxf(fmaxf(fminf(b1, o1), o2), b2);
        if (o1 > b1 || (o1 == b1 && oi < iq)) { b1 = o1; iq = oi; }
    }

    if (b1 - b2 < MARGIN_THR) {
        fidx[row] = iq;                       // placeholder; recheck overwrites
        flags[atomicAdd(cnt, 1)] = row;
    } else {
        // exact fp32 argmax within the winning quad (codes iq..iq+3)
        float xr[64];
        const float* xb = x + (row >> 10) * 65536 + (row & 1023);
#pragma unroll
        for (int c = 0; c < 64; ++c) xr[c] = xb[c * 1024];
        float best = -3.4e38f; int bi = iq;
#pragma unroll
        for (int cc = 0; cc < 4; ++cc) {
            const int j = iq + cc;
            const float* e = eT + j * 64;
            float s = bias[j];
#pragma unroll
            for (int c = 0; c < 64; ++c) s = fmaf(xr[c], e[c], s);
            if (s > best) { best = s; bi = j; }   // strict >, ascending j
        }
        fidx[row] = bi;
    }
}

// ---- K4: exact fp32 rescan of flagged rows (coalesced over embed's j axis)
__global__ __launch_bounds__(256) void recheck(const float* __restrict__ x,
                                               const float* __restrict__ embed, char* ws) {
    __shared__ float fl[64];
    __shared__ u64 red[256];
    const float* bias = (const float*)(ws + WS_BIAS);
    const int* flags = (const int*)(ws + WS_FLAG);
    const int n = *(const int*)(ws + WS_CNT);
    int* fidx = (int*)(ws + WS_FIDX);
    const int t = threadIdx.x;
    for (int fi = blockIdx.x; fi < n; fi += gridDim.x) {
        const int row = flags[fi];
        __syncthreads();
        if (t < 64) fl[t] = x[(row >> 10) * 65536 + t * 1024 + (row & 1023)];
        __syncthreads();
        float lb = -3.4e38f; int li = 0;
        for (int j = t; j < N_EMBED; j += 256) {
            float s = bias[j];
#pragma unroll
            for (int c = 0; c < 64; ++c) s = fmaf(fl[c], embed[c * N_EMBED + j], s);
            if (s > lb) { lb = s; li = j; }
        }
        red[t] = ((u64)f32_key(lb) << 32) | (u32)(~(u32)li);
        __syncthreads();
        for (int off = 128; off; off >>= 1) {
            if (t < off) { u64 o = red[t + off]; if (o > red[t]) red[t] = o; }
            __syncthreads();
        }
        if (t == 0) fidx[row] = (int)(~(u32)red[0]);
    }
}

// ---- K5: gather winning codes (exact fp32 from embedT)
__global__ __launch_bounds__(256) void gather_out(const char* __restrict__ ws,
                                                  float* __restrict__ out) {
    const int* fidx = (const int*)(ws + WS_FIDX);
    const float* eT = (const float*)(ws + WS_ET);
    int g = blockIdx.x * 256 + threadIdx.x;
    int row = g >> 6, c = g & 63;
    out[g] = eT[fidx[row] * 64 + c];
}

extern "C" void kernel_launch(void* const* d_in, const int* in_sizes, int n_in,
                              void* d_out, int out_size, void* d_ws, size_t ws_size,
                              hipStream_t stream) {
    const float* x     = (const float*)d_in[0];
    const float* embed = (const float*)d_in[1];
    float* out = (float*)d_out;
    char* ws = (char*)d_ws;

    prep<<<384, 256, 0, stream>>>(x, embed, ws);
    qdist<<<N_ROWBLK * NCHUNK, 256, 0, stream>>>(ws, ws);
    reduce_rows<<<N_ROWS / 256, 256, 0, stream>>>(x, ws);
    recheck<<<128, 256, 0, stream>>>(x, embed, ws);
    gather_out<<<(N_ROWS * 64) / 256, 256, 0, stream>>>(ws, out);
}

// Round 7
// 290.086 us; speedup vs baseline: 2.3466x; 2.3466x over previous
//
#include <hip/hip_runtime.h>

// Quantizer via bf16x3-split MFMA GEMM + exact-fp32 recheck of near-ties.
//   x: [16,64,32,32] fp32, embed: [64,8192] fp32
//   out[row][c] = embedT[argmax_j (f_row.e_j - ||e_j||^2/2)][c]
//
// R7: R6 with recheck fixed (R6's embed-layout scan was latency-serialized at
// VGPR=40 -> 480 us). recheck reads eT contiguously, pixel vector held in
// registers, 4 independent accumulators -> loads pipeline.

typedef __attribute__((ext_vector_type(8))) __bf16 bf16x8;
typedef __attribute__((ext_vector_type(4))) float f32x4;
typedef unsigned int u32;
typedef unsigned long long u64;

union frag_cast { f32x4 f; bf16x8 b; };
__device__ __forceinline__ bf16x8 as_bf16x8(f32x4 v) { frag_cast u; u.f = v; return u.b; }

#define N_ROWS  16384
#define E_DIM   64
#define N_EMBED 8192
#define NCHUNK  8
#define COLS_PER_BLOCK (N_EMBED / NCHUNK)   // 1024
#define N_ST (COLS_PER_BLOCK / 64)          // 16
#define ROWS_PER_BLOCK 128                  // 4 waves x 32 pixels
#define N_ROWBLK (N_ROWS / ROWS_PER_BLOCK)  // 128
#define MARGIN_THR 2e-3f

// ---- workspace byte offsets (~9.7 MB total)
#define WS_AH   0u              // pixel hi  [16384][64] bf16
#define WS_AL   (2u << 20)      // pixel lo
#define WS_BH   (4u << 20)      // code  hi  [8192][64] bf16 (128 B/code)
#define WS_BL   (5u << 20)      // code  lo
#define WS_ET   (6u << 20)      // embedT fp32 [8192][64]
#define WS_BIAS (8u << 20)      // -||e_j||^2/2
#define WS_PB1  (WS_BIAS + (64u << 10))
#define WS_PI1  (WS_PB1 + (512u << 10))
#define WS_PB2  (WS_PI1 + (512u << 10))
#define WS_FIDX (WS_PB2 + (512u << 10))
#define WS_FLAG (WS_FIDX + (64u << 10))
#define WS_CNT  (WS_FLAG + (64u << 10))

__device__ __forceinline__ u32 f32_key(float s) {
    u32 u = __float_as_uint(s);
    return (u & 0x80000000u) ? ~u : (u | 0x80000000u);
}

// ---- K1: prep. Blocks 0..255: split x -> A_hi/A_lo [row][64] bf16.
//          Blocks 256..383: transpose embed tile -> embedT fp32, B_hi/B_lo, bias.
__global__ __launch_bounds__(256) void prep(
        const float* __restrict__ x, const float* __restrict__ embed, char* ws) {
    __shared__ float tile[64][65];
    __bf16* Ah = (__bf16*)(ws + WS_AH);
    __bf16* Al = (__bf16*)(ws + WS_AL);
    __bf16* Bh = (__bf16*)(ws + WS_BH);
    __bf16* Bl = (__bf16*)(ws + WS_BL);
    float*  eT = (float*)(ws + WS_ET);
    float*  bias = (float*)(ws + WS_BIAS);
    const int t = threadIdx.x;
    const int blk = blockIdx.x;

    if (blk < 256) {
        const int b = blk >> 4, p0 = (blk & 15) * 64;
        {
            const int c = t >> 2, seg = (t & 3) * 16;
            const float* src = x + b * 65536 + c * 1024 + p0 + seg;
#pragma unroll
            for (int i = 0; i < 16; ++i) tile[c][seg + i] = src[i];
        }
        __syncthreads();
        const int p = t >> 2, cq = (t & 3) * 16;
        const long row = b * 1024 + p0 + p;
        bf16x8 vh0, vh1, vl0, vl1;
#pragma unroll
        for (int i = 0; i < 16; ++i) {
            float f = tile[cq + i][p];
            __bf16 h = (__bf16)f;
            __bf16 l = (__bf16)(f - (float)h);
            if (i < 8) { vh0[i] = h; vl0[i] = l; }
            else       { vh1[i - 8] = h; vl1[i - 8] = l; }
        }
        *(bf16x8*)(Ah + row * 64 + cq) = vh0;
        *(bf16x8*)(Ah + row * 64 + cq + 8) = vh1;
        *(bf16x8*)(Al + row * 64 + cq) = vl0;
        *(bf16x8*)(Al + row * 64 + cq + 8) = vl1;
    } else {
        if (blk == 256 && t == 0) *(int*)(ws + WS_CNT) = 0;
        const int jbase = (blk - 256) * 64;
        {
            const int c = t >> 2, seg = (t & 3) * 16;
            const float* src = embed + c * N_EMBED + jbase + seg;
#pragma unroll
            for (int i = 0; i < 16; ++i) tile[c][seg + i] = src[i];
        }
        __syncthreads();
        if (t < 64) {
            float s = 0.f;
#pragma unroll
            for (int c = 0; c < 64; ++c) { float v = tile[c][t]; s = fmaf(v, v, s); }
            bias[jbase + t] = -0.5f * s;
        }
        const int jl = t >> 2, cq = (t & 3) * 16;
        const long row = jbase + jl;
        bf16x8 vh0, vh1, vl0, vl1;
#pragma unroll
        for (int i = 0; i < 16; ++i) {
            float f = tile[cq + i][jl];
            eT[row * 64 + cq + i] = f;
            __bf16 h = (__bf16)f;
            __bf16 l = (__bf16)(f - (float)h);
            if (i < 8) { vh0[i] = h; vl0[i] = l; }
            else       { vh1[i - 8] = h; vl1[i - 8] = l; }
        }
        *(bf16x8*)(Bh + row * 64 + cq) = vh0;
        *(bf16x8*)(Bh + row * 64 + cq + 8) = vh1;
        *(bf16x8*)(Bl + row * 64 + cq) = vl0;
        *(bf16x8*)(Bl + row * 64 + cq + 8) = vl1;
    }
}

// ---- K2: MFMA GEMM + running (quad-max top-2) argmax. 1024 blocks, 4/CU.
__global__ __launch_bounds__(256, 4) void qdist(const char* __restrict__ ws_c, char* ws) {
    const __bf16* Ah = (const __bf16*)(ws_c + WS_AH);
    const __bf16* Al = (const __bf16*)(ws_c + WS_AL);
    const char* ChB = ws_c + WS_BH;    // code hi, 128 B per code
    const char* ClB = ws_c + WS_BL;
    const float* biasg = (const float*)(ws_c + WS_BIAS);
    float* pb1 = (float*)(ws + WS_PB1);
    int*   pi1 = (int*)(ws + WS_PI1);
    float* pb2 = (float*)(ws + WS_PB2);

    const int t = threadIdx.x;
    const int wv = t >> 6, lane = t & 63, ln = lane & 15, q = lane >> 4;
    const int rb = blockIdx.x >> 3, chunk = blockIdx.x & 7;
    const int row0 = rb * ROWS_PER_BLOCK;
    const int col0 = chunk * COLS_PER_BLOCK;

    // resident pixel fragments (B-operand): 2 pixel-tiles x 2 K-halves x {hi,lo}
    f32x4 pfh[2][2], pfl[2][2];
#pragma unroll
    for (int nt = 0; nt < 2; ++nt) {
        long row = row0 + wv * 32 + nt * 16 + ln;
        long base = row * 64 + q * 8;
        pfh[nt][0] = *(const f32x4*)(Ah + base);
        pfh[nt][1] = *(const f32x4*)(Ah + base + 32);
        pfl[nt][0] = *(const f32x4*)(Al + base);
        pfl[nt][1] = *(const f32x4*)(Al + base + 32);
    }
    // pin: volatile asm barrier — scheduler cannot sink/remat these loads into
    // the loop (R5: it did exactly that, VGPR_Count 44, latency-bound, 136 us)
    asm volatile("" : "+v"(pfh[0][0]), "+v"(pfh[0][1]), "+v"(pfh[1][0]), "+v"(pfh[1][1]),
                      "+v"(pfl[0][0]), "+v"(pfl[0][1]), "+v"(pfl[1][0]), "+v"(pfl[1][1]));

    float b1[2] = {-3.4e38f, -3.4e38f};
    float b2[2] = {-3.4e38f, -3.4e38f};
    int   iq[2] = {0, 0};

    const int laneoff = ln * 128 + q * 16;   // byte offset within a 16-code tile

#pragma unroll 2
    for (int st = 0; st < N_ST; ++st) {
#pragma unroll
        for (int ct = 0; ct < 4; ++ct) {
            const int cbase = col0 + st * 64 + ct * 16;   // first code of tile
            const char* ch = ChB + ((size_t)cbase << 7);
            const char* cl = ClB + ((size_t)cbase << 7);
            // code fragments (A-operand): coalesced 1KB wave loads
            bf16x8 ah0 = *(const bf16x8*)(ch + laneoff);
            bf16x8 ah1 = *(const bf16x8*)(ch + laneoff + 64);
            bf16x8 al0 = *(const bf16x8*)(cl + laneoff);
            bf16x8 al1 = *(const bf16x8*)(cl + laneoff + 64);
            f32x4 bv = *(const f32x4*)(biasg + cbase + q * 4);  // bias for 4 codes
            const int jq = cbase + q * 4;
#pragma unroll
            for (int nt = 0; nt < 2; ++nt) {
                f32x4 acc = __builtin_amdgcn_mfma_f32_16x16x32_bf16(al0, as_bf16x8(pfh[nt][0]), bv, 0, 0, 0);
                acc = __builtin_amdgcn_mfma_f32_16x16x32_bf16(al1, as_bf16x8(pfh[nt][1]), acc, 0, 0, 0);
                acc = __builtin_amdgcn_mfma_f32_16x16x32_bf16(ah0, as_bf16x8(pfl[nt][0]), acc, 0, 0, 0);
                acc = __builtin_amdgcn_mfma_f32_16x16x32_bf16(ah1, as_bf16x8(pfl[nt][1]), acc, 0, 0, 0);
                acc = __builtin_amdgcn_mfma_f32_16x16x32_bf16(ah0, as_bf16x8(pfh[nt][0]), acc, 0, 0, 0);
                acc = __builtin_amdgcn_mfma_f32_16x16x32_bf16(ah1, as_bf16x8(pfh[nt][1]), acc, 0, 0, 0);
                // quad max (4 codes of one pixel): 7 VALU total
                float mx = fmaxf(fmaxf(acc[0], acc[1]), fmaxf(acc[2], acc[3]));
                b2[nt] = fmaxf(b2[nt], fminf(b1[nt], mx));   // 2nd-best quad-max
                bool gt = mx > b1[nt];
                b1[nt] = fmaxf(b1[nt], mx);
                iq[nt] = gt ? jq : iq[nt];
            }
        }
    }

    // merge across the 4 quads (same pixel lives in lanes ln, ln+16, ln+32, ln+48)
#pragma unroll
    for (int m = 16; m < 64; m <<= 1) {
#pragma unroll
        for (int nt = 0; nt < 2; ++nt) {
            float o1 = __shfl_xor(b1[nt], m);
            int   oi = __shfl_xor(iq[nt], m);
            float o2 = __shfl_xor(b2[nt], m);
            b2[nt] = fmaxf(fmaxf(fminf(b1[nt], o1), o2), b2[nt]);
            bool take = (o1 > b1[nt]) || (o1 == b1[nt] && oi < iq[nt]);
            if (take) { b1[nt] = o1; iq[nt] = oi; }
        }
    }
    if (q == 0) {
#pragma unroll
        for (int nt = 0; nt < 2; ++nt) {
            int pixel = row0 + wv * 32 + nt * 16 + ln;
            int o = chunk * N_ROWS + pixel;
            pb1[o] = b1[nt];
            pi1[o] = iq[nt];
            pb2[o] = b2[nt];
        }
    }
}

// ---- K3: merge chunks per row; exact fp32 pick within winning quad;
//          flag near-ties (quad-max margin) for full exact recheck.
__global__ __launch_bounds__(256) void reduce_rows(const float* __restrict__ x, char* ws) {
    const float* pb1 = (const float*)(ws + WS_PB1);
    const int*   pi1 = (const int*)(ws + WS_PI1);
    const float* pb2 = (const float*)(ws + WS_PB2);
    const float* eT = (const float*)(ws + WS_ET);
    const float* bias = (const float*)(ws + WS_BIAS);
    int* fidx = (int*)(ws + WS_FIDX);
    int* flags = (int*)(ws + WS_FLAG);
    int* cnt = (int*)(ws + WS_CNT);
    const int row = blockIdx.x * 256 + threadIdx.x;

    float b1 = pb1[row]; int iq = pi1[row]; float b2 = pb2[row];
#pragma unroll
    for (int ch = 1; ch < NCHUNK; ++ch) {
        float o1 = pb1[ch * N_ROWS + row];
        int   oi = pi1[ch * N_ROWS + row];
        float o2 = pb2[ch * N_ROWS + row];
        b2 = fmaxf(fmaxf(fminf(b1, o1), o2), b2);
        if (o1 > b1 || (o1 == b1 && oi < iq)) { b1 = o1; iq = oi; }
    }

    if (b1 - b2 < MARGIN_THR) {
        fidx[row] = iq;                       // placeholder; recheck overwrites
        flags[atomicAdd(cnt, 1)] = row;
    } else {
        // exact fp32 argmax within the winning quad (codes iq..iq+3)
        float xr[64];
        const float* xb = x + (row >> 10) * 65536 + (row & 1023);
#pragma unroll
        for (int c = 0; c < 64; ++c) xr[c] = xb[c * 1024];
        float best = -3.4e38f; int bi = iq;
#pragma unroll
        for (int cc = 0; cc < 4; ++cc) {
            const int j = iq + cc;
            const float* e = eT + j * 64;
            float s = bias[j];
#pragma unroll
            for (int c = 0; c < 64; ++c) s = fmaf(xr[c], e[c], s);
            if (s > best) { best = s; bi = j; }   // strict >, ascending j
        }
        fidx[row] = bi;
    }
}

// ---- K4: exact fp32 rescan of flagged rows (eT layout: contiguous 256B/thread)
__global__ __launch_bounds__(256) void recheck(const float* __restrict__ x, char* ws) {
    __shared__ float fl[64];
    __shared__ u64 red[256];
    const float* eT = (const float*)(ws + WS_ET);
    const float* bias = (const float*)(ws + WS_BIAS);
    const int* flags = (const int*)(ws + WS_FLAG);
    const int n = *(const int*)(ws + WS_CNT);
    int* fidx = (int*)(ws + WS_FIDX);
    const int t = threadIdx.x;
    for (int fi = blockIdx.x; fi < n; fi += gridDim.x) {
        const int row = flags[fi];
        __syncthreads();
        if (t < 64) fl[t] = x[(row >> 10) * 65536 + t * 1024 + (row & 1023)];
        __syncthreads();
        // pixel vector into registers once (64 LDS broadcast reads)
        float xr[64];
#pragma unroll
        for (int c = 0; c < 64; ++c) xr[c] = fl[c];
        float lb = -3.4e38f; int li = 0;
        for (int j = t; j < N_EMBED; j += 256) {
            const f32x4* e = (const f32x4*)(eT + j * 64);
            // 4 independent accumulator chains; 16 float4 loads in flight
            f32x4 a0 = {0.f, 0.f, 0.f, 0.f}, a1 = a0, a2 = a0, a3 = a0;
#pragma unroll
            for (int v = 0; v < 4; ++v) {
                f32x4 e0 = e[v * 4 + 0], e1 = e[v * 4 + 1];
                f32x4 e2 = e[v * 4 + 2], e3 = e[v * 4 + 3];
#pragma unroll
                for (int k = 0; k < 4; ++k) {
                    a0[k] = fmaf(xr[v * 16 + k],      e0[k], a0[k]);
                    a1[k] = fmaf(xr[v * 16 + 4 + k],  e1[k], a1[k]);
                    a2[k] = fmaf(xr[v * 16 + 8 + k],  e2[k], a2[k]);
                    a3[k] = fmaf(xr[v * 16 + 12 + k], e3[k], a3[k]);
                }
            }
            f32x4 a01 = a0 + a1, a23 = a2 + a3;
            f32x4 as = a01 + a23;
            float s = bias[j] + ((as[0] + as[1]) + (as[2] + as[3]));
            if (s > lb) { lb = s; li = j; }
        }
        red[t] = ((u64)f32_key(lb) << 32) | (u32)(~(u32)li);
        __syncthreads();
        for (int off = 128; off; off >>= 1) {
            if (t < off) { u64 o = red[t + off]; if (o > red[t]) red[t] = o; }
            __syncthreads();
        }
        if (t == 0) fidx[row] = (int)(~(u32)red[0]);
        __syncthreads();
    }
}

// ---- K5: gather winning codes (exact fp32 from embedT)
__global__ __launch_bounds__(256) void gather_out(const char* __restrict__ ws,
                                                  float* __restrict__ out) {
    const int* fidx = (const int*)(ws + WS_FIDX);
    const float* eT = (const float*)(ws + WS_ET);
    int g = blockIdx.x * 256 + threadIdx.x;
    int row = g >> 6, c = g & 63;
    out[g] = eT[fidx[row] * 64 + c];
}

extern "C" void kernel_launch(void* const* d_in, const int* in_sizes, int n_in,
                              void* d_out, int out_size, void* d_ws, size_t ws_size,
                              hipStream_t stream) {
    const float* x     = (const float*)d_in[0];
    const float* embed = (const float*)d_in[1];
    float* out = (float*)d_out;
    char* ws = (char*)d_ws;

    prep<<<384, 256, 0, stream>>>(x, embed, ws);
    qdist<<<N_ROWBLK * NCHUNK, 256, 0, stream>>>(ws, ws);
    reduce_rows<<<N_ROWS / 256, 256, 0, stream>>>(x, ws);
    recheck<<<256, 256, 0, stream>>>(x, ws);
    gather_out<<<(N_ROWS * 64) / 256, 256, 0, stream>>>(ws, out);
}

// Round 8
// 208.578 us; speedup vs baseline: 3.2637x; 1.3908x over previous
//
#include <hip/hip_runtime.h>

// Quantizer via bf16x3-split MFMA GEMM + exact-fp32 recheck of near-ties.
//   x: [16,64,32,32] fp32, embed: [64,8192] fp32
//   out[row][c] = embedT[argmax_j (f_row.e_j - ||e_j||^2/2)][c]
//
// R8: codes staged per-block into LDS (global_load_lds w=16, double-buffered,
// 1 barrier/stage) instead of per-wave global streaming (R5/R7 was L1-BW
// bound: MfmaUtil 15%). 512 pixels/block resident in VGPRs; granule-XOR
// swizzle in ws makes the LDS fragment reads bank-conflict-free while
// keeping the staging source contiguous.

typedef __attribute__((ext_vector_type(8))) __bf16 bf16x8;
typedef __attribute__((ext_vector_type(4))) float f32x4;
typedef unsigned int u32;
typedef unsigned long long u64;

union frag_cast { f32x4 f; bf16x8 b; };
__device__ __forceinline__ bf16x8 as_bf16x8(f32x4 v) { frag_cast u; u.f = v; return u.b; }

#define N_ROWS  16384
#define E_DIM   64
#define N_EMBED 8192
#define NCHUNK  16
#define COLS_PER_BLOCK (N_EMBED / NCHUNK)   // 512
#define N_ST (COLS_PER_BLOCK / 64)          // 8 stages of 64 codes
#define ROWS_PER_BLOCK 512                  // 4 waves x 128 pixels
#define N_ROWBLK (N_ROWS / ROWS_PER_BLOCK)  // 32
#define MARGIN_THR 2e-3f

// ---- workspace byte offsets (~11.4 MB total)
#define WS_AH   0u              // pixel hi  [16384][64] bf16 (2 MB)
#define WS_AL   (2u << 20)      // pixel lo  (2 MB)
#define WS_B    (4u << 20)      // codes: 128 groups x [hi 64x128B | lo 64x128B] (2 MB)
#define WS_ET   (6u << 20)      // embedT fp32 [8192][64] (2 MB)
#define WS_BIAS (8u << 20)      // -||e_j||^2/2 (32 KB)
#define WS_PB1  (WS_BIAS + (64u << 10))     // 1 MB
#define WS_PI1  (WS_PB1 + (1u << 20))       // 1 MB
#define WS_PB2  (WS_PI1 + (1u << 20))       // 1 MB
#define WS_FIDX (WS_PB2 + (1u << 20))       // 64 KB
#define WS_FLAG (WS_FIDX + (64u << 10))     // 64 KB
#define WS_CNT  (WS_FLAG + (64u << 10))

__device__ __forceinline__ u32 f32_key(float s) {
    u32 u = __float_as_uint(s);
    return (u & 0x80000000u) ? ~u : (u | 0x80000000u);
}

__device__ __forceinline__ void async16(const void* g, void* l) {
    __builtin_amdgcn_global_load_lds(
        (const __attribute__((address_space(1))) void*)g,
        (__attribute__((address_space(3))) void*)l, 16, 0, 0);
}

// ---- K1: prep. Blocks 0..255: split x -> A_hi/A_lo [row][64] bf16.
//          Blocks 256..383: embedT fp32, bias, and swizzled interleaved code groups.
__global__ __launch_bounds__(256) void prep(
        const float* __restrict__ x, const float* __restrict__ embed, char* ws) {
    __shared__ float tile[64][65];
    __bf16* Ah = (__bf16*)(ws + WS_AH);
    __bf16* Al = (__bf16*)(ws + WS_AL);
    float*  eT = (float*)(ws + WS_ET);
    float*  bias = (float*)(ws + WS_BIAS);
    const int t = threadIdx.x;
    const int blk = blockIdx.x;

    if (blk < 256) {
        const int b = blk >> 4, p0 = (blk & 15) * 64;
        {
            const int c = t >> 2, seg = (t & 3) * 16;
            const float* src = x + b * 65536 + c * 1024 + p0 + seg;
#pragma unroll
            for (int i = 0; i < 16; ++i) tile[c][seg + i] = src[i];
        }
        __syncthreads();
        const int p = t >> 2, cq = (t & 3) * 16;
        const long row = b * 1024 + p0 + p;
        bf16x8 vh0, vh1, vl0, vl1;
#pragma unroll
        for (int i = 0; i < 16; ++i) {
            float f = tile[cq + i][p];
            __bf16 h = (__bf16)f;
            __bf16 l = (__bf16)(f - (float)h);
            if (i < 8) { vh0[i] = h; vl0[i] = l; }
            else       { vh1[i - 8] = h; vl1[i - 8] = l; }
        }
        *(bf16x8*)(Ah + row * 64 + cq) = vh0;
        *(bf16x8*)(Ah + row * 64 + cq + 8) = vh1;
        *(bf16x8*)(Al + row * 64 + cq) = vl0;
        *(bf16x8*)(Al + row * 64 + cq + 8) = vl1;
    } else {
        if (blk == 256 && t == 0) *(int*)(ws + WS_CNT) = 0;
        const int g = blk - 256;             // 64-code group
        const int jbase = g * 64;
        char* Bg = ws + WS_B + (size_t)g * 16384;
        {
            const int c = t >> 2, seg = (t & 3) * 16;
            const float* src = embed + c * N_EMBED + jbase + seg;
#pragma unroll
            for (int i = 0; i < 16; ++i) tile[c][seg + i] = src[i];
        }
        __syncthreads();
        if (t < 64) {
            float s = 0.f;
#pragma unroll
            for (int c = 0; c < 64; ++c) { float v = tile[c][t]; s = fmaf(v, v, s); }
            bias[jbase + t] = -0.5f * s;
        }
        const int jl = t >> 2, cq = (t & 3) * 16;   // channels cq..cq+15
        bf16x8 vh0, vh1, vl0, vl1;
#pragma unroll
        for (int i = 0; i < 16; ++i) {
            float f = tile[cq + i][jl];
            eT[(long)(jbase + jl) * 64 + cq + i] = f;
            __bf16 h = (__bf16)f;
            __bf16 l = (__bf16)(f - (float)h);
            if (i < 8) { vh0[i] = h; vl0[i] = l; }
            else       { vh1[i - 8] = h; vl1[i - 8] = l; }
        }
        // granule-XOR swizzle: logical granule k (8 bf16) of code jl stored at
        // position k ^ (jl & 7). Keeps staging contiguous, LDS reads conflict-free.
        const int k0 = (cq >> 3), sw = jl & 7;
        __bf16* hi = (__bf16*)Bg + jl * 64;
        __bf16* lo = (__bf16*)(Bg + 8192) + jl * 64;
        *(bf16x8*)(hi + ((k0 ^ sw) * 8))       = vh0;
        *(bf16x8*)(hi + (((k0 + 1) ^ sw) * 8)) = vh1;
        *(bf16x8*)(lo + ((k0 ^ sw) * 8))       = vl0;
        *(bf16x8*)(lo + (((k0 + 1) ^ sw) * 8)) = vl1;
    }
}

// ---- K2: MFMA GEMM + running (quad-max top-2) argmax.
// grid 512 blocks (32 rowblk x 16 chunks), 256 thr, 2 blocks/CU.
__global__ __launch_bounds__(256, 2) void qdist(const char* __restrict__ ws_c, char* __restrict__ ws) {
    __shared__ __align__(16) char smem[2][16384];
    const __bf16* Ah = (const __bf16*)(ws_c + WS_AH);
    const __bf16* Al = (const __bf16*)(ws_c + WS_AL);
    const char* Bws = ws_c + WS_B;
    const float* biasg = (const float*)(ws_c + WS_BIAS);
    float* pb1 = (float*)(ws + WS_PB1);
    int*   pi1 = (int*)(ws + WS_PI1);
    float* pb2 = (float*)(ws + WS_PB2);

    const int t = threadIdx.x;
    const int wv = t >> 6, lane = t & 63, ln = lane & 15, q = lane >> 4;
    const int rb = blockIdx.x >> 4, chunk = blockIdx.x & 15;
    const int row0 = rb * ROWS_PER_BLOCK;
    const int col0 = chunk * COLS_PER_BLOCK;
    const int g0 = col0 >> 6;               // first 64-code group of this chunk

    // resident pixel fragments (B-operand): 8 pixel-tiles x 2 K-halves x {hi,lo}
    f32x4 pfh[8][2], pfl[8][2];
#pragma unroll
    for (int nt = 0; nt < 8; ++nt) {
        long row = row0 + wv * 128 + nt * 16 + ln;
        long base = row * 64 + q * 8;
        pfh[nt][0] = *(const f32x4*)(Ah + base);
        pfh[nt][1] = *(const f32x4*)(Ah + base + 32);
        pfl[nt][0] = *(const f32x4*)(Al + base);
        pfl[nt][1] = *(const f32x4*)(Al + base + 32);
    }
    asm volatile("" :
        "+v"(pfh[0][0]), "+v"(pfh[0][1]), "+v"(pfh[1][0]), "+v"(pfh[1][1]),
        "+v"(pfh[2][0]), "+v"(pfh[2][1]), "+v"(pfh[3][0]), "+v"(pfh[3][1]),
        "+v"(pfh[4][0]), "+v"(pfh[4][1]), "+v"(pfh[5][0]), "+v"(pfh[5][1]),
        "+v"(pfh[6][0]), "+v"(pfh[6][1]), "+v"(pfh[7][0]), "+v"(pfh[7][1]));
    asm volatile("" :
        "+v"(pfl[0][0]), "+v"(pfl[0][1]), "+v"(pfl[1][0]), "+v"(pfl[1][1]),
        "+v"(pfl[2][0]), "+v"(pfl[2][1]), "+v"(pfl[3][0]), "+v"(pfl[3][1]),
        "+v"(pfl[4][0]), "+v"(pfl[4][1]), "+v"(pfl[5][0]), "+v"(pfl[5][1]),
        "+v"(pfl[6][0]), "+v"(pfl[6][1]), "+v"(pfl[7][0]), "+v"(pfl[7][1]));

    float b1[8], b2[8]; int iq[8];
#pragma unroll
    for (int k = 0; k < 8; ++k) { b1[k] = -3.4e38f; b2[k] = -3.4e38f; iq[k] = 0; }

    // swizzled fragment read offsets: code cl=ct*16+ln; hi-K0 granule q^(ln&7)
    const int s7 = ln & 7;
    const int rdbase = ln * 128 + ((q ^ s7) << 4);

    auto issue = [&](int st) {
        const char* src = Bws + (size_t)(g0 + st) * 16384;
        char* dst = smem[st & 1];
#pragma unroll
        for (int s = 0; s < 4; ++s)
            async16(src + s * 4096 + wv * 1024 + lane * 16,
                    dst + s * 4096 + wv * 1024);
    };

    issue(0);
    for (int st = 0; st < N_ST; ++st) {
        __syncthreads();                 // own staging drained (vmcnt0 before barrier);
        if (st + 1 < N_ST) issue(st + 1);// all waves done reading buf[(st+1)&1]
        const char* buf = smem[st & 1];
#pragma unroll
        for (int ct = 0; ct < 4; ++ct) {
            const int boff = ct * 2048 + rdbase;
            bf16x8 ah0 = *(const bf16x8*)(buf + boff);
            bf16x8 ah1 = *(const bf16x8*)(buf + (boff ^ 64));
            bf16x8 al0 = *(const bf16x8*)(buf + 8192 + boff);
            bf16x8 al1 = *(const bf16x8*)(buf + 8192 + (boff ^ 64));
            const int cbase = col0 + st * 64 + ct * 16;
            f32x4 bv = *(const f32x4*)(biasg + cbase + q * 4);  // bias for 4 codes
            const int jq = cbase + q * 4;
#pragma unroll
            for (int nt = 0; nt < 8; ++nt) {
                f32x4 acc = __builtin_amdgcn_mfma_f32_16x16x32_bf16(al0, as_bf16x8(pfh[nt][0]), bv, 0, 0, 0);
                acc = __builtin_amdgcn_mfma_f32_16x16x32_bf16(al1, as_bf16x8(pfh[nt][1]), acc, 0, 0, 0);
                acc = __builtin_amdgcn_mfma_f32_16x16x32_bf16(ah0, as_bf16x8(pfl[nt][0]), acc, 0, 0, 0);
                acc = __builtin_amdgcn_mfma_f32_16x16x32_bf16(ah1, as_bf16x8(pfl[nt][1]), acc, 0, 0, 0);
                acc = __builtin_amdgcn_mfma_f32_16x16x32_bf16(ah0, as_bf16x8(pfh[nt][0]), acc, 0, 0, 0);
                acc = __builtin_amdgcn_mfma_f32_16x16x32_bf16(ah1, as_bf16x8(pfh[nt][1]), acc, 0, 0, 0);
                // quad max (4 codes of one pixel)
                float mx = fmaxf(fmaxf(acc[0], acc[1]), fmaxf(acc[2], acc[3]));
                b2[nt] = fmaxf(b2[nt], fminf(b1[nt], mx));
                bool gt = mx > b1[nt];
                b1[nt] = fmaxf(b1[nt], mx);
                iq[nt] = gt ? jq : iq[nt];
            }
        }
    }

    // merge across the 4 quads (same pixel lives in lanes ln, ln+16, ln+32, ln+48)
#pragma unroll
    for (int m = 16; m < 64; m <<= 1) {
#pragma unroll
        for (int nt = 0; nt < 8; ++nt) {
            float o1 = __shfl_xor(b1[nt], m);
            int   oi = __shfl_xor(iq[nt], m);
            float o2 = __shfl_xor(b2[nt], m);
            b2[nt] = fmaxf(fmaxf(fminf(b1[nt], o1), o2), b2[nt]);
            bool take = (o1 > b1[nt]) || (o1 == b1[nt] && oi < iq[nt]);
            if (take) { b1[nt] = o1; iq[nt] = oi; }
        }
    }
    if (q == 0) {
#pragma unroll
        for (int nt = 0; nt < 8; ++nt) {
            int pixel = row0 + wv * 128 + nt * 16 + ln;
            int o = chunk * N_ROWS + pixel;
            pb1[o] = b1[nt];
            pi1[o] = iq[nt];
            pb2[o] = b2[nt];
        }
    }
}

// ---- K3: merge chunks per row; exact fp32 pick within winning quad;
//          flag near-ties (quad-max margin) for full exact recheck.
__global__ __launch_bounds__(256) void reduce_rows(const float* __restrict__ x, char* ws) {
    const float* pb1 = (const float*)(ws + WS_PB1);
    const int*   pi1 = (const int*)(ws + WS_PI1);
    const float* pb2 = (const float*)(ws + WS_PB2);
    const float* eT = (const float*)(ws + WS_ET);
    const float* bias = (const float*)(ws + WS_BIAS);
    int* fidx = (int*)(ws + WS_FIDX);
    int* flags = (int*)(ws + WS_FLAG);
    int* cnt = (int*)(ws + WS_CNT);
    const int row = blockIdx.x * 256 + threadIdx.x;

    float b1 = pb1[row]; int iq = pi1[row]; float b2 = pb2[row];
#pragma unroll
    for (int ch = 1; ch < NCHUNK; ++ch) {
        float o1 = pb1[ch * N_ROWS + row];
        int   oi = pi1[ch * N_ROWS + row];
        float o2 = pb2[ch * N_ROWS + row];
        b2 = fmaxf(fmaxf(fminf(b1, o1), o2), b2);
        if (o1 > b1 || (o1 == b1 && oi < iq)) { b1 = o1; iq = oi; }
    }

    if (b1 - b2 < MARGIN_THR) {
        fidx[row] = iq;                       // placeholder; recheck overwrites
        flags[atomicAdd(cnt, 1)] = row;
    } else {
        // exact fp32 argmax within the winning quad (codes iq..iq+3)
        float xr[64];
        const float* xb = x + (row >> 10) * 65536 + (row & 1023);
#pragma unroll
        for (int c = 0; c < 64; ++c) xr[c] = xb[c * 1024];
        float best = -3.4e38f; int bi = iq;
#pragma unroll
        for (int cc = 0; cc < 4; ++cc) {
            const int j = iq + cc;
            const float* e = eT + j * 64;
            float s = bias[j];
#pragma unroll
            for (int c = 0; c < 64; ++c) s = fmaf(xr[c], e[c], s);
            if (s > best) { best = s; bi = j; }   // strict >, ascending j
        }
        fidx[row] = bi;
    }
}

// ---- K4: exact fp32 rescan of flagged rows (eT layout: contiguous 256B/thread)
__global__ __launch_bounds__(256) void recheck(const float* __restrict__ x, char* ws) {
    __shared__ float fl[64];
    __shared__ u64 red[256];
    const float* eT = (const float*)(ws + WS_ET);
    const float* bias = (const float*)(ws + WS_BIAS);
    const int* flags = (const int*)(ws + WS_FLAG);
    const int n = *(const int*)(ws + WS_CNT);
    int* fidx = (int*)(ws + WS_FIDX);
    const int t = threadIdx.x;
    for (int fi = blockIdx.x; fi < n; fi += gridDim.x) {
        const int row = flags[fi];
        __syncthreads();
        if (t < 64) fl[t] = x[(row >> 10) * 65536 + t * 1024 + (row & 1023)];
        __syncthreads();
        float xr[64];
#pragma unroll
        for (int c = 0; c < 64; ++c) xr[c] = fl[c];
        float lb = -3.4e38f; int li = 0;
        for (int j = t; j < N_EMBED; j += 256) {
            const f32x4* e = (const f32x4*)(eT + j * 64);
            f32x4 a0 = {0.f, 0.f, 0.f, 0.f}, a1 = a0, a2 = a0, a3 = a0;
#pragma unroll
            for (int v = 0; v < 4; ++v) {
                f32x4 e0 = e[v * 4 + 0], e1 = e[v * 4 + 1];
                f32x4 e2 = e[v * 4 + 2], e3 = e[v * 4 + 3];
#pragma unroll
                for (int k = 0; k < 4; ++k) {
                    a0[k] = fmaf(xr[v * 16 + k],      e0[k], a0[k]);
                    a1[k] = fmaf(xr[v * 16 + 4 + k],  e1[k], a1[k]);
                    a2[k] = fmaf(xr[v * 16 + 8 + k],  e2[k], a2[k]);
                    a3[k] = fmaf(xr[v * 16 + 12 + k], e3[k], a3[k]);
                }
            }
            f32x4 a01 = a0 + a1, a23 = a2 + a3;
            f32x4 as = a01 + a23;
            float s = bias[j] + ((as[0] + as[1]) + (as[2] + as[3]));
            if (s > lb) { lb = s; li = j; }
        }
        red[t] = ((u64)f32_key(lb) << 32) | (u32)(~(u32)li);
        __syncthreads();
        for (int off = 128; off; off >>= 1) {
            if (t < off) { u64 o = red[t + off]; if (o > red[t]) red[t] = o; }
            __syncthreads();
        }
        if (t == 0) fidx[row] = (int)(~(u32)red[0]);
        __syncthreads();
    }
}

// ---- K5: gather winning codes (exact fp32 from embedT)
__global__ __launch_bounds__(256) void gather_out(const char* __restrict__ ws,
                                                  float* __restrict__ out) {
    const int* fidx = (const int*)(ws + WS_FIDX);
    const float* eT = (const float*)(ws + WS_ET);
    int g = blockIdx.x * 256 + threadIdx.x;
    int row = g >> 6, c = g & 63;
    out[g] = eT[fidx[row] * 64 + c];
}

extern "C" void kernel_launch(void* const* d_in, const int* in_sizes, int n_in,
                              void* d_out, int out_size, void* d_ws, size_t ws_size,
                              hipStream_t stream) {
    const float* x     = (const float*)d_in[0];
    const float* embed = (const float*)d_in[1];
    float* out = (float*)d_out;
    char* ws = (char*)d_ws;

    prep<<<384, 256, 0, stream>>>(x, embed, ws);
    qdist<<<N_ROWBLK * NCHUNK, 256, 0, stream>>>(ws, ws);
    reduce_rows<<<N_ROWS / 256, 256, 0, stream>>>(x, ws);
    recheck<<<256, 256, 0, stream>>>(x, ws);
    gather_out<<<(N_ROWS * 64) / 256, 256, 0, stream>>>(ws, out);
}

// Round 9
// 136.780 us; speedup vs baseline: 4.9768x; 1.5249x over previous
//
#include <hip/hip_runtime.h>

// Quantizer via bf16x3-split MFMA GEMM + exact-fp32 recheck of near-ties.
//   x: [16,64,32,32] fp32, embed: [64,8192] fp32
//   out[row][c] = embedT[argmax_j (f_row.e_j - ||e_j||^2/2)][c]
//
// R9: recheck parallelized across the code axis (R8: one block per flagged
// row scanned 8192 codes serially -> 0.96% occupancy, latency-bound 90 us).
// Now 32 blocks/row x 256 codes/block, merged via u64 atomicMax on
// (sortable-score | ~j); gather decodes flagged rows from the key.

typedef __attribute__((ext_vector_type(8))) __bf16 bf16x8;
typedef __attribute__((ext_vector_type(4))) float f32x4;
typedef unsigned int u32;
typedef unsigned long long u64;

union frag_cast { f32x4 f; bf16x8 b; };
__device__ __forceinline__ bf16x8 as_bf16x8(f32x4 v) { frag_cast u; u.f = v; return u.b; }

#define N_ROWS  16384
#define E_DIM   64
#define N_EMBED 8192
#define NCHUNK  16
#define COLS_PER_BLOCK (N_EMBED / NCHUNK)   // 512
#define N_ST (COLS_PER_BLOCK / 64)          // 8 stages of 64 codes
#define ROWS_PER_BLOCK 512                  // 4 waves x 128 pixels
#define N_ROWBLK (N_ROWS / ROWS_PER_BLOCK)  // 32
#define MARGIN_THR 2e-3f

// ---- workspace byte offsets (~11.6 MB total)
#define WS_AH   0u              // pixel hi  [16384][64] bf16 (2 MB)
#define WS_AL   (2u << 20)      // pixel lo  (2 MB)
#define WS_B    (4u << 20)      // codes: 128 groups x [hi 64x128B | lo 64x128B] (2 MB)
#define WS_ET   (6u << 20)      // embedT fp32 [8192][64] (2 MB)
#define WS_BIAS (8u << 20)      // -||e_j||^2/2 (32 KB)
#define WS_PB1  (WS_BIAS + (64u << 10))     // 1 MB
#define WS_PI1  (WS_PB1 + (1u << 20))       // 1 MB
#define WS_PB2  (WS_PI1 + (1u << 20))       // 1 MB
#define WS_FIDX (WS_PB2 + (1u << 20))       // 64 KB
#define WS_FLAG (WS_FIDX + (64u << 10))     // 64 KB
#define WS_CNT  (WS_FLAG + (64u << 10))     // 4 KB
#define WS_FKEY (WS_CNT + (4u << 10))       // 128 KB u64 keys

__device__ __forceinline__ u32 f32_key(float s) {
    u32 u = __float_as_uint(s);
    return (u & 0x80000000u) ? ~u : (u | 0x80000000u);
}

__device__ __forceinline__ void async16(const void* g, void* l) {
    __builtin_amdgcn_global_load_lds(
        (const __attribute__((address_space(1))) void*)g,
        (__attribute__((address_space(3))) void*)l, 16, 0, 0);
}

// ---- K1: prep. Blocks 0..255: split x -> A_hi/A_lo [row][64] bf16.
//          Blocks 256..383: embedT fp32, bias, and swizzled interleaved code groups.
__global__ __launch_bounds__(256) void prep(
        const float* __restrict__ x, const float* __restrict__ embed, char* ws) {
    __shared__ float tile[64][65];
    __bf16* Ah = (__bf16*)(ws + WS_AH);
    __bf16* Al = (__bf16*)(ws + WS_AL);
    float*  eT = (float*)(ws + WS_ET);
    float*  bias = (float*)(ws + WS_BIAS);
    const int t = threadIdx.x;
    const int blk = blockIdx.x;

    if (blk < 256) {
        const int b = blk >> 4, p0 = (blk & 15) * 64;
        {
            const int c = t >> 2, seg = (t & 3) * 16;
            const float* src = x + b * 65536 + c * 1024 + p0 + seg;
#pragma unroll
            for (int i = 0; i < 16; ++i) tile[c][seg + i] = src[i];
        }
        __syncthreads();
        const int p = t >> 2, cq = (t & 3) * 16;
        const long row = b * 1024 + p0 + p;
        bf16x8 vh0, vh1, vl0, vl1;
#pragma unroll
        for (int i = 0; i < 16; ++i) {
            float f = tile[cq + i][p];
            __bf16 h = (__bf16)f;
            __bf16 l = (__bf16)(f - (float)h);
            if (i < 8) { vh0[i] = h; vl0[i] = l; }
            else       { vh1[i - 8] = h; vl1[i - 8] = l; }
        }
        *(bf16x8*)(Ah + row * 64 + cq) = vh0;
        *(bf16x8*)(Ah + row * 64 + cq + 8) = vh1;
        *(bf16x8*)(Al + row * 64 + cq) = vl0;
        *(bf16x8*)(Al + row * 64 + cq + 8) = vl1;
    } else {
        if (blk == 256 && t == 0) *(int*)(ws + WS_CNT) = 0;
        const int g = blk - 256;             // 64-code group
        const int jbase = g * 64;
        char* Bg = ws + WS_B + (size_t)g * 16384;
        {
            const int c = t >> 2, seg = (t & 3) * 16;
            const float* src = embed + c * N_EMBED + jbase + seg;
#pragma unroll
            for (int i = 0; i < 16; ++i) tile[c][seg + i] = src[i];
        }
        __syncthreads();
        if (t < 64) {
            float s = 0.f;
#pragma unroll
            for (int c = 0; c < 64; ++c) { float v = tile[c][t]; s = fmaf(v, v, s); }
            bias[jbase + t] = -0.5f * s;
        }
        const int jl = t >> 2, cq = (t & 3) * 16;   // channels cq..cq+15
        bf16x8 vh0, vh1, vl0, vl1;
#pragma unroll
        for (int i = 0; i < 16; ++i) {
            float f = tile[cq + i][jl];
            eT[(long)(jbase + jl) * 64 + cq + i] = f;
            __bf16 h = (__bf16)f;
            __bf16 l = (__bf16)(f - (float)h);
            if (i < 8) { vh0[i] = h; vl0[i] = l; }
            else       { vh1[i - 8] = h; vl1[i - 8] = l; }
        }
        // granule-XOR swizzle: logical granule k (8 bf16) of code jl stored at
        // position k ^ (jl & 7). Keeps staging contiguous, LDS reads conflict-free.
        const int k0 = (cq >> 3), sw = jl & 7;
        __bf16* hi = (__bf16*)Bg + jl * 64;
        __bf16* lo = (__bf16*)(Bg + 8192) + jl * 64;
        *(bf16x8*)(hi + ((k0 ^ sw) * 8))       = vh0;
        *(bf16x8*)(hi + (((k0 + 1) ^ sw) * 8)) = vh1;
        *(bf16x8*)(lo + ((k0 ^ sw) * 8))       = vl0;
        *(bf16x8*)(lo + (((k0 + 1) ^ sw) * 8)) = vl1;
    }
}

// ---- K2: MFMA GEMM + running (quad-max top-2) argmax.
// grid 512 blocks (32 rowblk x 16 chunks), 256 thr, 2 blocks/CU.
__global__ __launch_bounds__(256, 2) void qdist(const char* __restrict__ ws_c, char* __restrict__ ws) {
    __shared__ __align__(16) char smem[2][16384];
    const __bf16* Ah = (const __bf16*)(ws_c + WS_AH);
    const __bf16* Al = (const __bf16*)(ws_c + WS_AL);
    const char* Bws = ws_c + WS_B;
    const float* biasg = (const float*)(ws_c + WS_BIAS);
    float* pb1 = (float*)(ws + WS_PB1);
    int*   pi1 = (int*)(ws + WS_PI1);
    float* pb2 = (float*)(ws + WS_PB2);

    const int t = threadIdx.x;
    const int wv = t >> 6, lane = t & 63, ln = lane & 15, q = lane >> 4;
    const int rb = blockIdx.x >> 4, chunk = blockIdx.x & 15;
    const int row0 = rb * ROWS_PER_BLOCK;
    const int col0 = chunk * COLS_PER_BLOCK;
    const int g0 = col0 >> 6;               // first 64-code group of this chunk

    // resident pixel fragments (B-operand): 8 pixel-tiles x 2 K-halves x {hi,lo}
    f32x4 pfh[8][2], pfl[8][2];
#pragma unroll
    for (int nt = 0; nt < 8; ++nt) {
        long row = row0 + wv * 128 + nt * 16 + ln;
        long base = row * 64 + q * 8;
        pfh[nt][0] = *(const f32x4*)(Ah + base);
        pfh[nt][1] = *(const f32x4*)(Ah + base + 32);
        pfl[nt][0] = *(const f32x4*)(Al + base);
        pfl[nt][1] = *(const f32x4*)(Al + base + 32);
    }
    asm volatile("" :
        "+v"(pfh[0][0]), "+v"(pfh[0][1]), "+v"(pfh[1][0]), "+v"(pfh[1][1]),
        "+v"(pfh[2][0]), "+v"(pfh[2][1]), "+v"(pfh[3][0]), "+v"(pfh[3][1]),
        "+v"(pfh[4][0]), "+v"(pfh[4][1]), "+v"(pfh[5][0]), "+v"(pfh[5][1]),
        "+v"(pfh[6][0]), "+v"(pfh[6][1]), "+v"(pfh[7][0]), "+v"(pfh[7][1]));
    asm volatile("" :
        "+v"(pfl[0][0]), "+v"(pfl[0][1]), "+v"(pfl[1][0]), "+v"(pfl[1][1]),
        "+v"(pfl[2][0]), "+v"(pfl[2][1]), "+v"(pfl[3][0]), "+v"(pfl[3][1]),
        "+v"(pfl[4][0]), "+v"(pfl[4][1]), "+v"(pfl[5][0]), "+v"(pfl[5][1]),
        "+v"(pfl[6][0]), "+v"(pfl[6][1]), "+v"(pfl[7][0]), "+v"(pfl[7][1]));

    float b1[8], b2[8]; int iq[8];
#pragma unroll
    for (int k = 0; k < 8; ++k) { b1[k] = -3.4e38f; b2[k] = -3.4e38f; iq[k] = 0; }

    // swizzled fragment read offsets: code cl=ct*16+ln; hi-K0 granule q^(ln&7)
    const int s7 = ln & 7;
    const int rdbase = ln * 128 + ((q ^ s7) << 4);

    auto issue = [&](int st) {
        const char* src = Bws + (size_t)(g0 + st) * 16384;
        char* dst = smem[st & 1];
#pragma unroll
        for (int s = 0; s < 4; ++s)
            async16(src + s * 4096 + wv * 1024 + lane * 16,
                    dst + s * 4096 + wv * 1024);
    };

    issue(0);
    for (int st = 0; st < N_ST; ++st) {
        __syncthreads();                 // own staging drained (vmcnt0 before barrier);
        if (st + 1 < N_ST) issue(st + 1);// all waves done reading buf[(st+1)&1]
        const char* buf = smem[st & 1];
#pragma unroll
        for (int ct = 0; ct < 4; ++ct) {
            const int boff = ct * 2048 + rdbase;
            bf16x8 ah0 = *(const bf16x8*)(buf + boff);
            bf16x8 ah1 = *(const bf16x8*)(buf + (boff ^ 64));
            bf16x8 al0 = *(const bf16x8*)(buf + 8192 + boff);
            bf16x8 al1 = *(const bf16x8*)(buf + 8192 + (boff ^ 64));
            const int cbase = col0 + st * 64 + ct * 16;
            f32x4 bv = *(const f32x4*)(biasg + cbase + q * 4);  // bias for 4 codes
            const int jq = cbase + q * 4;
#pragma unroll
            for (int nt = 0; nt < 8; ++nt) {
                f32x4 acc = __builtin_amdgcn_mfma_f32_16x16x32_bf16(al0, as_bf16x8(pfh[nt][0]), bv, 0, 0, 0);
                acc = __builtin_amdgcn_mfma_f32_16x16x32_bf16(al1, as_bf16x8(pfh[nt][1]), acc, 0, 0, 0);
                acc = __builtin_amdgcn_mfma_f32_16x16x32_bf16(ah0, as_bf16x8(pfl[nt][0]), acc, 0, 0, 0);
                acc = __builtin_amdgcn_mfma_f32_16x16x32_bf16(ah1, as_bf16x8(pfl[nt][1]), acc, 0, 0, 0);
                acc = __builtin_amdgcn_mfma_f32_16x16x32_bf16(ah0, as_bf16x8(pfh[nt][0]), acc, 0, 0, 0);
                acc = __builtin_amdgcn_mfma_f32_16x16x32_bf16(ah1, as_bf16x8(pfh[nt][1]), acc, 0, 0, 0);
                // quad max (4 codes of one pixel)
                float mx = fmaxf(fmaxf(acc[0], acc[1]), fmaxf(acc[2], acc[3]));
                b2[nt] = fmaxf(b2[nt], fminf(b1[nt], mx));
                bool gt = mx > b1[nt];
                b1[nt] = fmaxf(b1[nt], mx);
                iq[nt] = gt ? jq : iq[nt];
            }
        }
    }

    // merge across the 4 quads (same pixel lives in lanes ln, ln+16, ln+32, ln+48)
#pragma unroll
    for (int m = 16; m < 64; m <<= 1) {
#pragma unroll
        for (int nt = 0; nt < 8; ++nt) {
            float o1 = __shfl_xor(b1[nt], m);
            int   oi = __shfl_xor(iq[nt], m);
            float o2 = __shfl_xor(b2[nt], m);
            b2[nt] = fmaxf(fmaxf(fminf(b1[nt], o1), o2), b2[nt]);
            bool take = (o1 > b1[nt]) || (o1 == b1[nt] && oi < iq[nt]);
            if (take) { b1[nt] = o1; iq[nt] = oi; }
        }
    }
    if (q == 0) {
#pragma unroll
        for (int nt = 0; nt < 8; ++nt) {
            int pixel = row0 + wv * 128 + nt * 16 + ln;
            int o = chunk * N_ROWS + pixel;
            pb1[o] = b1[nt];
            pi1[o] = iq[nt];
            pb2[o] = b2[nt];
        }
    }
}

// ---- K3: merge chunks per row; exact fp32 pick within winning quad;
//          flag near-ties (quad-max margin) for parallel exact recheck.
__global__ __launch_bounds__(256) void reduce_rows(const float* __restrict__ x, char* ws) {
    const float* pb1 = (const float*)(ws + WS_PB1);
    const int*   pi1 = (const int*)(ws + WS_PI1);
    const float* pb2 = (const float*)(ws + WS_PB2);
    const float* eT = (const float*)(ws + WS_ET);
    const float* bias = (const float*)(ws + WS_BIAS);
    int* fidx = (int*)(ws + WS_FIDX);
    int* flags = (int*)(ws + WS_FLAG);
    int* cnt = (int*)(ws + WS_CNT);
    u64* fkey = (u64*)(ws + WS_FKEY);
    const int row = blockIdx.x * 256 + threadIdx.x;

    float b1 = pb1[row]; int iq = pi1[row]; float b2 = pb2[row];
#pragma unroll
    for (int ch = 1; ch < NCHUNK; ++ch) {
        float o1 = pb1[ch * N_ROWS + row];
        int   oi = pi1[ch * N_ROWS + row];
        float o2 = pb2[ch * N_ROWS + row];
        b2 = fmaxf(fmaxf(fminf(b1, o1), o2), b2);
        if (o1 > b1 || (o1 == b1 && oi < iq)) { b1 = o1; iq = oi; }
    }

    if (b1 - b2 < MARGIN_THR) {
        fidx[row] = -1;                       // marker: decode from fkey
        fkey[row] = 0ull;                     // any finite score key > 0
        flags[atomicAdd(cnt, 1)] = row;
    } else {
        // exact fp32 argmax within the winning quad (codes iq..iq+3)
        float xr[64];
        const float* xb = x + (row >> 10) * 65536 + (row & 1023);
#pragma unroll
        for (int c = 0; c < 64; ++c) xr[c] = xb[c * 1024];
        float best = -3.4e38f; int bi = iq;
#pragma unroll
        for (int cc = 0; cc < 4; ++cc) {
            const int j = iq + cc;
            const float* e = eT + j * 64;
            float s = bias[j];
#pragma unroll
            for (int c = 0; c < 64; ++c) s = fmaf(xr[c], e[c], s);
            if (s > best) { best = s; bi = j; }   // strict >, ascending j
        }
        fidx[row] = bi;
    }
}

// ---- K4: exact fp32 rescan of flagged rows, 32 blocks/row x 256 codes/block
//          (one code per thread: 16 independent contiguous f32x4 loads).
__global__ __launch_bounds__(256) void recheck(const float* __restrict__ x, char* ws) {
    __shared__ float fl[64];
    __shared__ u64 red[256];
    const float* eT = (const float*)(ws + WS_ET);
    const float* bias = (const float*)(ws + WS_BIAS);
    const int* flags = (const int*)(ws + WS_FLAG);
    const int n = *(const int*)(ws + WS_CNT);
    u64* fkey = (u64*)(ws + WS_FKEY);
    const int t = threadIdx.x;
    const int seg = blockIdx.x & 31;
    const int rstep = gridDim.x >> 5;
    const int j = seg * 256 + t;             // this thread's code

    for (int rowi = blockIdx.x >> 5; rowi < n; rowi += rstep) {
        const int row = flags[rowi];
        __syncthreads();
        if (t < 64) fl[t] = x[(row >> 10) * 65536 + t * 1024 + (row & 1023)];
        __syncthreads();
        float xr[64];
#pragma unroll
        for (int c = 0; c < 64; ++c) xr[c] = fl[c];

        const f32x4* e = (const f32x4*)(eT + (size_t)j * 64);
        f32x4 a0 = {0.f, 0.f, 0.f, 0.f}, a1 = a0, a2 = a0, a3 = a0;
#pragma unroll
        for (int v = 0; v < 4; ++v) {
            f32x4 e0 = e[v * 4 + 0], e1 = e[v * 4 + 1];
            f32x4 e2 = e[v * 4 + 2], e3 = e[v * 4 + 3];
#pragma unroll
            for (int k = 0; k < 4; ++k) {
                a0[k] = fmaf(xr[v * 16 + k],      e0[k], a0[k]);
                a1[k] = fmaf(xr[v * 16 + 4 + k],  e1[k], a1[k]);
                a2[k] = fmaf(xr[v * 16 + 8 + k],  e2[k], a2[k]);
                a3[k] = fmaf(xr[v * 16 + 12 + k], e3[k], a3[k]);
            }
        }
        f32x4 a01 = a0 + a1, a23 = a2 + a3;
        f32x4 as = a01 + a23;
        float s = bias[j] + ((as[0] + as[1]) + (as[2] + as[3]));

        red[t] = ((u64)f32_key(s) << 32) | (u32)(~(u32)j);
        __syncthreads();
        for (int off = 128; off; off >>= 1) {
            if (t < off) { u64 o = red[t + off]; if (o > red[t]) red[t] = o; }
            __syncthreads();
        }
        if (t == 0) atomicMax(&fkey[row], red[0]);
        __syncthreads();
    }
}

// ---- K5: gather winning codes; flagged rows decode from fkey
__global__ __launch_bounds__(256) void gather_out(const char* __restrict__ ws,
                                                  float* __restrict__ out) {
    const int* fidx = (const int*)(ws + WS_FIDX);
    const u64* fkey = (const u64*)(ws + WS_FKEY);
    const float* eT = (const float*)(ws + WS_ET);
    int g = blockIdx.x * 256 + threadIdx.x;
    int row = g >> 6, c = g & 63;
    int idx = fidx[row];
    if (idx < 0) idx = (int)(~(u32)(fkey[row] & 0xffffffffull));
    out[g] = eT[idx * 64 + c];
}

extern "C" void kernel_launch(void* const* d_in, const int* in_sizes, int n_in,
                              void* d_out, int out_size, void* d_ws, size_t ws_size,
                              hipStream_t stream) {
    const float* x     = (const float*)d_in[0];
    const float* embed = (const float*)d_in[1];
    float* out = (float*)d_out;
    char* ws = (char*)d_ws;

    prep<<<384, 256, 0, stream>>>(x, embed, ws);
    qdist<<<N_ROWBLK * NCHUNK, 256, 0, stream>>>(ws, ws);
    reduce_rows<<<N_ROWS / 256, 256, 0, stream>>>(x, ws);
    recheck<<<2048, 256, 0, stream>>>(x, ws);
    gather_out<<<(N_ROWS * 64) / 256, 256, 0, stream>>>(ws, out);
}